// Round 10
// baseline (130.581 us; speedup 1.0000x reference)
//
#include <hip/hip_runtime.h>
#include <hip/hip_bf16.h>
#include <stdint.h>
#include <stddef.h>

#define B_ 2
#define T_ 2048
#define C_ 1024
#define H_ 16
#define D_ 64
#define M_ (B_*T_)   // 4096

typedef __attribute__((ext_vector_type(8))) short short8;
typedef __attribute__((ext_vector_type(4))) float f32x4;
typedef __attribute__((ext_vector_type(16))) float f32x16;
typedef __attribute__((ext_vector_type(4))) unsigned int u32x4;

__device__ __forceinline__ unsigned short f2bf(float f) {
    unsigned u = __float_as_uint(f);
    unsigned r = 0x7FFFu + ((u >> 16) & 1u);
    return (unsigned short)((u + r) >> 16);
}

__device__ __forceinline__ unsigned cvtpk_bf16(float lo, float hi) {
    unsigned r;
    asm("v_cvt_pk_bf16_f32 %0, %1, %2" : "=v"(r) : "v"(lo), "v"(hi));
    return r;
}

// guaranteed single-instruction 2^x
__device__ __forceinline__ float fexp2(float x) {
    float r;
    asm("v_exp_f32 %0, %1" : "=v"(r) : "v"(x));
    return r;
}

// v_permlane32_swap_b32: a = [a_lo | b_lo], b = [a_hi | b_hi]
__device__ __forceinline__ void plswap(unsigned &a, unsigned &b) {
    asm("v_permlane32_swap_b32 %0, %1" : "+v"(a), "+v"(b));
}

__device__ __forceinline__ float xhalf_max(float v) {
    float a = v, b = v;
    asm("" : "+v"(b));
    asm("v_permlane32_swap_b32 %0, %1" : "+v"(a), "+v"(b));
    return fmaxf(a, b);
}
__device__ __forceinline__ float xhalf_sum(float v) {
    float a = v, b = v;
    asm("" : "+v"(b));
    asm("v_permlane32_swap_b32 %0, %1" : "+v"(a), "+v"(b));
    return a + b;
}

__device__ __forceinline__ void gload16(const void* g, void* l) {
    __builtin_amdgcn_global_load_lds(
        (__attribute__((address_space(1))) void*)g,
        (__attribute__((address_space(3))) void*)l,
        16, 0, 0);
}

// ---------------- fp32 -> bf16 conversion ----------------
__global__ void cvt_bf16(const float* __restrict__ in,
                         unsigned short* __restrict__ out, int n) {
    int idx = (blockIdx.x * blockDim.x + threadIdx.x) * 4;
    if (idx >= n) return;
    float4 v = *reinterpret_cast<const float4*>(in + idx);
    ushort4 o;
    o.x = f2bf(v.x); o.y = f2bf(v.y); o.z = f2bf(v.z); o.w = f2bf(v.w);
    *reinterpret_cast<ushort4*>(out + idx) = o;
}

__global__ void cvt_bf16_w4(const float* __restrict__ a, const float* __restrict__ b,
                            const float* __restrict__ c, const float* __restrict__ d,
                            unsigned short* __restrict__ oa, unsigned short* __restrict__ ob,
                            unsigned short* __restrict__ oc, unsigned short* __restrict__ od,
                            int n) {
    int idx = (blockIdx.x * blockDim.x + threadIdx.x) * 4;
    if (idx >= n) return;
    const float* in = (blockIdx.y == 0) ? a : (blockIdx.y == 1) ? b : (blockIdx.y == 2) ? c : d;
    unsigned short* out = (blockIdx.y == 0) ? oa : (blockIdx.y == 1) ? ob : (blockIdx.y == 2) ? oc : od;
    float4 v = *reinterpret_cast<const float4*>(in + idx);
    ushort4 o;
    o.x = f2bf(v.x); o.y = f2bf(v.y); o.z = f2bf(v.z); o.w = f2bf(v.w);
    *reinterpret_cast<ushort4*>(out + idx) = o;
}

// ---------------- fused QKV projection GEMM (BK=64, swizzled LDS) ----------------
// which 0 -> K [B,H,T,D], which 1 -> Q*scale [B,H,T,D], which 2 -> V^T [B,H,D,T]
__global__ __launch_bounds__(256) void gemm_qkv(
    const unsigned short* __restrict__ A,
    const unsigned short* __restrict__ W0,
    const unsigned short* __restrict__ W1,
    const unsigned short* __restrict__ W2,
    const float* __restrict__ b0,
    const float* __restrict__ b1,
    const float* __restrict__ b2,
    unsigned short* __restrict__ o0,   // k
    unsigned short* __restrict__ o1,   // q (pre-scaled by LOG2E/32)
    unsigned short* __restrict__ o2)   // vt
{
    __shared__ unsigned short As[128*64];   // 16 KB, XOR-swizzled 16B slots
    __shared__ unsigned short Bs[128*64];
    int which = blockIdx.x >> 8;
    int bx = blockIdx.x & 255;
    int bm = bx >> 3, bn = bx & 7;
    const unsigned short* W = (which==0) ? W0 : ((which==1) ? W1 : W2);
    const float* bias = (which==0) ? b0 : ((which==1) ? b1 : b2);

    int tid = threadIdx.x;
    int lane = tid & 63;
    int fr = lane & 15, fq = lane >> 4;
    int wid = tid >> 6;
    int wr = wid >> 1, wc = wid & 1;
    int r7 = fr & 7;

    int arow = tid >> 3;                          // 0..31 (slab-local row)
    int aslot = ((tid & 7) ^ (arow & 7)) << 3;    // pre-permuted source slot (shorts)
    const unsigned short* Ab = A + (size_t)(bm*128 + arow) * C_ + aslot;
    const unsigned short* Wb = W + (size_t)(bn*128 + arow) * C_ + aslot;

    f32x4 acc[4][4] = {};

    for (int kt = 0; kt < C_/64; ++kt) {
        int ko = kt*64;
        #pragma unroll
        for (int slab = 0; slab < 4; ++slab) {
            gload16(Ab + (size_t)slab*32*C_ + ko, &As[slab*2048 + tid*8]);
            gload16(Wb + (size_t)slab*32*C_ + ko, &Bs[slab*2048 + tid*8]);
        }
        __syncthreads();
        short8 af[4][2], bf[4][2];
        #pragma unroll
        for (int i = 0; i < 4; ++i) {
            int ra = (wr*64 + i*16 + fr)*64;
            int rb = (wc*64 + i*16 + fr)*64;
            #pragma unroll
            for (int h = 0; h < 2; ++h) {
                int sl = (((h<<2)|fq) ^ r7) * 8;
                af[i][h] = *reinterpret_cast<const short8*>(&As[ra + sl]);
                bf[i][h] = *reinterpret_cast<const short8*>(&Bs[rb + sl]);
            }
        }
        #pragma unroll
        for (int i = 0; i < 4; ++i)
            #pragma unroll
            for (int j = 0; j < 4; ++j) {
                acc[i][j] = __builtin_amdgcn_mfma_f32_16x16x32_bf16(af[i][0], bf[j][0], acc[i][j], 0, 0, 0);
                acc[i][j] = __builtin_amdgcn_mfma_f32_16x16x32_bf16(af[i][1], bf[j][1], acc[i][j], 0, 0, 0);
            }
        __syncthreads();
    }

    // Q: fold 1/sqrt(C)=1/32 AND log2(e) so QK^T lands in log2 domain
    float sc = (which == 1) ? 0.045084220f : 1.0f;
    int mbase = bm*128 + wr*64;
    int nbase = bn*128 + wc*64;
    #pragma unroll
    for (int j = 0; j < 4; ++j) {
        int col = nbase + j*16 + fr;
        float bv = bias[col];
        int h = col >> 6, d = col & 63;
        #pragma unroll
        for (int i = 0; i < 4; ++i) {
            int r0 = mbase + i*16 + fq*4;
            #pragma unroll
            for (int r = 0; r < 4; ++r) {
                float v = (acc[i][j][r] + bv) * sc;
                int m = r0 + r;
                int b = m >> 11, t = m & (T_-1);
                unsigned short hv = f2bf(v);
                if (which == 2)
                    o2[((size_t)(b*H_ + h)*D_ + d)*T_ + t] = hv;
                else {
                    unsigned short* o = (which==0) ? o0 : o1;
                    o[((size_t)(b*H_ + h)*T_ + t)*D_ + d] = hv;
                }
            }
        }
    }
}

// ---------------- output projection GEMM (BK=64, swizzled LDS) ----------------
__global__ __launch_bounds__(256) void gemm_out(
    const unsigned short* __restrict__ A,   // y bf16 [M_][C_]
    const unsigned short* __restrict__ W,   // Wo bf16 [C_][C_]
    const float* __restrict__ bias,
    float* __restrict__ out)
{
    __shared__ unsigned short As[128*64];
    __shared__ unsigned short Bs[128*64];
    int bx = blockIdx.x;
    int bm = bx >> 3, bn = bx & 7;

    int tid = threadIdx.x;
    int lane = tid & 63;
    int fr = lane & 15, fq = lane >> 4;
    int wid = tid >> 6;
    int wr = wid >> 1, wc = wid & 1;
    int r7 = fr & 7;

    int arow = tid >> 3;
    int aslot = ((tid & 7) ^ (arow & 7)) << 3;
    const unsigned short* Ab = A + (size_t)(bm*128 + arow) * C_ + aslot;
    const unsigned short* Wb = W + (size_t)(bn*128 + arow) * C_ + aslot;

    f32x4 acc[4][4] = {};

    for (int kt = 0; kt < C_/64; ++kt) {
        int ko = kt*64;
        #pragma unroll
        for (int slab = 0; slab < 4; ++slab) {
            gload16(Ab + (size_t)slab*32*C_ + ko, &As[slab*2048 + tid*8]);
            gload16(Wb + (size_t)slab*32*C_ + ko, &Bs[slab*2048 + tid*8]);
        }
        __syncthreads();
        short8 af[4][2], bf[4][2];
        #pragma unroll
        for (int i = 0; i < 4; ++i) {
            int ra = (wr*64 + i*16 + fr)*64;
            int rb = (wc*64 + i*16 + fr)*64;
            #pragma unroll
            for (int h = 0; h < 2; ++h) {
                int sl = (((h<<2)|fq) ^ r7) * 8;
                af[i][h] = *reinterpret_cast<const short8*>(&As[ra + sl]);
                bf[i][h] = *reinterpret_cast<const short8*>(&Bs[rb + sl]);
            }
        }
        #pragma unroll
        for (int i = 0; i < 4; ++i)
            #pragma unroll
            for (int j = 0; j < 4; ++j) {
                acc[i][j] = __builtin_amdgcn_mfma_f32_16x16x32_bf16(af[i][0], bf[j][0], acc[i][j], 0, 0, 0);
                acc[i][j] = __builtin_amdgcn_mfma_f32_16x16x32_bf16(af[i][1], bf[j][1], acc[i][j], 0, 0, 0);
            }
        __syncthreads();
    }

    int mbase = bm*128 + wr*64;
    int nbase = bn*128 + wc*64;
    #pragma unroll
    for (int j = 0; j < 4; ++j) {
        int col = nbase + j*16 + fr;
        float bv = bias[col];
        #pragma unroll
        for (int i = 0; i < 4; ++i) {
            int r0 = mbase + i*16 + fq*4;
            #pragma unroll
            for (int r = 0; r < 4; ++r)
                out[(size_t)(r0 + r)*C_ + col] = acc[i][j][r] + bv;
        }
    }
}

// ---------------- flash attention: staged + in-block 2-way KV split ----------------
// Block = 4 waves / 256 thr. Waves {0,1}: kv tiles [0,S+1); waves {2,3}: [S+1,2S+2).
// Wave pair (w, w+2) owns the same 64 q-rows (2 chains of 32). LDS merge at end.
__device__ __forceinline__ void attn_subtile(
    const short8 (&kf)[4], const short8 (&qf)[4],
    const short8 (&vlo)[2], const short8 (&vhi)[2],
    bool diag, int l31, int hi,
    f32x16& o0, f32x16& o1, float& m_, float& l_)
{
    // QK^T (swapped: A=K, B=Q): a0 col = q row (l31), row = kv_local
    f32x16 a0 = {};
    __builtin_amdgcn_s_setprio(1);
    a0 = __builtin_amdgcn_mfma_f32_32x32x16_bf16(kf[0], qf[0], a0, 0, 0, 0);
    a0 = __builtin_amdgcn_mfma_f32_32x32x16_bf16(kf[1], qf[1], a0, 0, 0, 0);
    a0 = __builtin_amdgcn_mfma_f32_32x32x16_bf16(kf[2], qf[2], a0, 0, 0, 0);
    a0 = __builtin_amdgcn_mfma_f32_32x32x16_bf16(kf[3], qf[3], a0, 0, 0, 0);
    __builtin_amdgcn_s_setprio(0);

    // causal mask: only the diagonal sub-tile
    if (diag) {
        #pragma unroll
        for (int r = 0; r < 16; ++r) {
            int kvl = (r&3) + 8*(r>>2) + 4*hi;
            if (kvl > l31) a0[r] = -1e30f;
        }
    }

    // row max: pairwise tree + cross-half swap
    float x0 = fmaxf(a0[0], a0[1]),   x1 = fmaxf(a0[2], a0[3]);
    float x2 = fmaxf(a0[4], a0[5]),   x3 = fmaxf(a0[6], a0[7]);
    float x4 = fmaxf(a0[8], a0[9]),   x5 = fmaxf(a0[10], a0[11]);
    float x6 = fmaxf(a0[12], a0[13]), x7 = fmaxf(a0[14], a0[15]);
    float y0 = fmaxf(x0, x1), y1 = fmaxf(x2, x3), y2 = fmaxf(x4, x5), y3 = fmaxf(x6, x7);
    float pm = fmaxf(fmaxf(y0, y1), fmaxf(y2, y3));
    pm = xhalf_max(pm);

    // defer-max (T13)
    if (!__all(pm - m_ <= 8.0f)) {
        float mn = fmaxf(m_, pm);
        float alpha = fexp2(m_ - mn);
        l_ *= alpha;
        m_ = mn;
        #pragma unroll
        for (int r = 0; r < 16; ++r) {
            int row = (r&3) + 8*(r>>2) + 4*hi;
            float ar = __shfl(alpha, row);
            o0[r] *= ar;
            o1[r] *= ar;
        }
    }

    // P = exp2(s - m); row sum via pairwise tree + cross-half swap
    #pragma unroll
    for (int r = 0; r < 16; ++r)
        a0[r] = fexp2(a0[r] - m_);
    float s0 = a0[0]+a0[1],  s1 = a0[2]+a0[3],  s2 = a0[4]+a0[5],   s3 = a0[6]+a0[7];
    float s4 = a0[8]+a0[9],  s5 = a0[10]+a0[11], s6 = a0[12]+a0[13], s7 = a0[14]+a0[15];
    float u0 = s0+s1, u1 = s2+s3, u2 = s4+s5, u3 = s6+s7;
    float rs = (u0+u1) + (u2+u3);
    rs = xhalf_sum(rs);
    l_ += rs;

    // pack P to bf16 pairs
    unsigned pk_[8];
    #pragma unroll
    for (int jj = 0; jj < 8; ++jj)
        pk_[jj] = cvtpk_bf16(a0[2*jj], a0[2*jj+1]);

    // PV: A-frag redistribution via permlane32_swap
    #pragma unroll
    for (int kb = 0; kb < 2; ++kb) {
        unsigned fx = pk_[4*kb+0], fz = pk_[4*kb+2];
        unsigned fy = pk_[4*kb+1], fw = pk_[4*kb+3];
        plswap(fx, fz);
        plswap(fy, fw);
        u32x4 wv;
        wv.x = fx; wv.y = fy; wv.z = fz; wv.w = fw;
        short8 pfrag = __builtin_bit_cast(short8, wv);
        __builtin_amdgcn_s_setprio(1);
        o0 = __builtin_amdgcn_mfma_f32_32x32x16_bf16(pfrag, vlo[kb], o0, 0, 0, 0);
        o1 = __builtin_amdgcn_mfma_f32_32x32x16_bf16(pfrag, vhi[kb], o1, 0, 0, 0);
        __builtin_amdgcn_s_setprio(0);
    }
}

__global__ __launch_bounds__(256, 2) void flash_attn(
    const unsigned short* __restrict__ q,
    const unsigned short* __restrict__ k,
    const unsigned short* __restrict__ vt,
    unsigned short* __restrict__ y)
{
    // staging: [buf][tensor][4096 shorts]; tensors: 0=K_lo 1=K_hi 2=V_lo 3=V_hi (64 KB)
    __shared__ __align__(16) unsigned short ST[2][4][4096];
    // merge overlay (used only after the final compute barrier):
    float* oP  = reinterpret_cast<float*>(&ST[0][0][0]);   // [4 sets][32 rows][68]
    float* mlP = oP + 4*32*68;                             // m: [set*32+l31], l: +128

    int tid = threadIdx.x, lane = tid & 63, w = tid >> 6;
    int l31 = lane & 31, hi = lane >> 5, rsw = l31 & 7;
    int role = w >> 1, pair = w & 1;
    int bid = blockIdx.x;

    // balanced complementary mapping: co-resident blocks (bid, bid+256) have S summing to 15
    int half = bid >> 8;              // 0 or 1
    int idx  = bid & 255;
    int bh   = (idx & 7)*4 + ((idx >> 3) & 3);   // 4 heads per XCD
    int sidx = idx >> 5;              // 0..7
    int S    = half ? sidx : (15 - sidx);        // heavy half first

    const unsigned short* kp = k  + (size_t)bh*T_*D_;
    const unsigned short* vp = vt + (size_t)bh*D_*T_;

    int rowbase = S*128 + pair*64;    // this wave-pair's first q row
    const unsigned short* qp = q + ((size_t)bh*T_ + rowbase) * D_;

    short8 qf0[4], qf1[4];
    #pragma unroll
    for (int dk = 0; dk < 4; ++dk) {
        qf0[dk] = *reinterpret_cast<const short8*>(qp + (size_t)l31*D_        + dk*16 + hi*8);
        qf1[dk] = *reinterpret_cast<const short8*>(qp + (size_t)(32 + l31)*D_ + dk*16 + hi*8);
    }

    f32x16 o00 = {}, o01 = {}, o10 = {}, o11 = {};
    float m0 = -1e30f, l0 = 0.f, m1 = -1e30f, l1 = 0.f;

    int lim0 = 4*S + 2*pair;          // chain0 diag sub-tile (global g)
    int lim1 = lim0 + 1;              // chain1
    int niter = S + 1;                // tiles per stream

    // stage iteration ii: low tile = ii, high tile = S+1+ii (512 chunks/tensor)
    #define STAGE(ii, bufi)                                                            \
    {                                                                                  \
        _Pragma("unroll")                                                              \
        for (int jj = 0; jj < 2; ++jj) {                                               \
            int c2 = tid + jj*256;                                                     \
            int row_ = c2 >> 3;                                                        \
            int slot_ = (c2 & 7) ^ (row_ & 7);                                         \
            int tl_ = (ii), th_ = S + 1 + (ii);                                        \
            gload16(kp + ((size_t)(tl_*64 + row_))*D_ + slot_*8, &ST[bufi][0][c2*8]);  \
            gload16(kp + ((size_t)(th_*64 + row_))*D_ + slot_*8, &ST[bufi][1][c2*8]);  \
            gload16(vp + (size_t)row_*T_ + tl_*64 + slot_*8,     &ST[bufi][2][c2*8]);  \
            gload16(vp + (size_t)row_*T_ + th_*64 + slot_*8,     &ST[bufi][3][c2*8]);  \
        }                                                                              \
    }

    STAGE(0, 0);
    __syncthreads();

    for (int i = 0; i < niter; ++i) {
        int bufi = i & 1;
        if (i + 1 < niter) STAGE(i + 1, bufi ^ 1);

        const unsigned short* Kl = &ST[bufi][role][0];
        const unsigned short* Vl = &ST[bufi][2 + role][0];
        int t = role ? (S + 1 + i) : i;

        #pragma unroll
        for (int st = 0; st < 2; ++st) {
            int g = 2*t + st;
            if (g <= lim1) {
                short8 kf[4];
                const unsigned short* kr = Kl + (st*32 + l31)*64;
                #pragma unroll
                for (int dk = 0; dk < 4; ++dk)
                    kf[dk] = *reinterpret_cast<const short8*>(kr + (((dk<<1)|hi) ^ rsw)*8);
                short8 vlo[2], vhi[2];
                const unsigned short* vr0 = Vl + l31*64;
                const unsigned short* vr1 = Vl + (32 + l31)*64;
                #pragma unroll
                for (int kb = 0; kb < 2; ++kb) {
                    int sl = (((st<<2) | (kb<<1) | hi) ^ rsw) * 8;
                    vlo[kb] = *reinterpret_cast<const short8*>(vr0 + sl);
                    vhi[kb] = *reinterpret_cast<const short8*>(vr1 + sl);
                }
                if (g <= lim0)
                    attn_subtile(kf, qf0, vlo, vhi, g == lim0, l31, hi, o00, o01, m0, l0);
                attn_subtile(kf, qf1, vlo, vhi, g == lim1, l31, hi, o10, o11, m1, l1);
            }
        }
        __syncthreads();
    }
    #undef STAGE

    // ---- merge the two KV halves (low waves store; high waves combine + write) ----
    if (!role) {
        int s0 = pair*2, s1 = pair*2 + 1;
        #pragma unroll
        for (int rr = 0; rr < 16; ++rr) {
            int crow = (rr&3) + 8*(rr>>2) + 4*hi;
            oP[(s0*32 + crow)*68 + l31]      = o00[rr];
            oP[(s0*32 + crow)*68 + 32 + l31] = o01[rr];
            oP[(s1*32 + crow)*68 + l31]      = o10[rr];
            oP[(s1*32 + crow)*68 + 32 + l31] = o11[rr];
        }
        if (!hi) {
            mlP[s0*32 + l31]       = m0;
            mlP[128 + s0*32 + l31] = l0;
            mlP[s1*32 + l31]       = m1;
            mlP[128 + s1*32 + l31] = l1;
        }
    }
    __syncthreads();
    if (role) {
        int b = bh >> 4, h = bh & 15;
        #pragma unroll
        for (int qq = 0; qq < 2; ++qq) {
            int set = pair*2 + qq;
            const f32x16& po0 = qq ? o10 : o00;
            const f32x16& po1 = qq ? o11 : o01;
            float m_ = qq ? m1 : m0;
            float l_ = qq ? l1 : l0;

            float mA = mlP[set*32 + l31];
            float lA = mlP[128 + set*32 + l31];
            float mN = fmaxf(mA, m_);
            float aA = fexp2(mA - mN);
            float aB = fexp2(m_ - mN);
            float lN = lA*aA + l_*aB;
            float inv = 1.0f / lN;
            float cA = aA * inv, cB = aB * inv;

            #pragma unroll
            for (int rr = 0; rr < 16; ++rr) {
                int crow = (rr&3) + 8*(rr>>2) + 4*hi;
                float cAr = __shfl(cA, crow);
                float cBr = __shfl(cB, crow);
                float vA0 = oP[(set*32 + crow)*68 + l31];
                float vA1 = oP[(set*32 + crow)*68 + 32 + l31];
                int trow = rowbase + qq*32 + crow;
                size_t base = ((size_t)(b*T_ + trow))*C_ + h*64;
                y[base + l31]      = f2bf(vA0*cAr + po0[rr]*cBr);
                y[base + 32 + l31] = f2bf(vA1*cAr + po1[rr]*cBr);
            }
        }
    }
}

extern "C" void kernel_launch(void* const* d_in, const int* in_sizes, int n_in,
                              void* d_out, int out_size, void* d_ws, size_t ws_size,
                              hipStream_t stream) {
    const float* x  = (const float*)d_in[0];
    const float* Wk = (const float*)d_in[1];
    const float* bk = (const float*)d_in[2];
    const float* Wq = (const float*)d_in[3];
    const float* bq = (const float*)d_in[4];
    const float* Wv = (const float*)d_in[5];
    const float* bv = (const float*)d_in[6];
    const float* Wo = (const float*)d_in[7];
    const float* bo = (const float*)d_in[8];
    float* out = (float*)d_out;

    char* ws = (char*)d_ws;
    unsigned short* xb  = (unsigned short*)(ws);                    // 8MB
    unsigned short* wkb = (unsigned short*)(ws + ((size_t)8  << 20));
    unsigned short* wqb = (unsigned short*)(ws + ((size_t)10 << 20));
    unsigned short* wvb = (unsigned short*)(ws + ((size_t)12 << 20));
    unsigned short* wob = (unsigned short*)(ws + ((size_t)14 << 20));
    unsigned short* qb  = (unsigned short*)(ws + ((size_t)16 << 20)); // [B,H,T,D]
    unsigned short* kb  = (unsigned short*)(ws + ((size_t)24 << 20)); // [B,H,T,D]
    unsigned short* vtb = (unsigned short*)(ws + ((size_t)32 << 20)); // [B,H,D,T]
    unsigned short* yb  = (unsigned short*)(ws + ((size_t)40 << 20)); // [B*T,C]

    const int nx = B_*T_*C_;   // 4M
    const int nw = C_*C_;      // 1M

    cvt_bf16<<<dim3(nx/4/256), dim3(256), 0, stream>>>(x, xb, nx);
    cvt_bf16_w4<<<dim3(nw/4/256, 4), dim3(256), 0, stream>>>(
        Wk, Wq, Wv, Wo, wkb, wqb, wvb, wob, nw);

    gemm_qkv<<<dim3(768), dim3(256), 0, stream>>>(xb, wkb, wqb, wvb, bk, bq, bv, kb, qb, vtb);

    flash_attn<<<dim3(512), dim3(256), 0, stream>>>(qb, kb, vtb, yb);

    gemm_out<<<dim3(256), dim3(256), 0, stream>>>(yb, wob, bo, out);
}

// Round 11
// 115.189 us; speedup vs baseline: 1.1336x; 1.1336x over previous
//
#include <hip/hip_runtime.h>
#include <hip/hip_bf16.h>
#include <stdint.h>
#include <stddef.h>

#define B_ 2
#define T_ 2048
#define C_ 1024
#define H_ 16
#define D_ 64
#define M_ (B_*T_)   // 4096

typedef __attribute__((ext_vector_type(8))) short short8;
typedef __attribute__((ext_vector_type(4))) float f32x4;
typedef __attribute__((ext_vector_type(16))) float f32x16;
typedef __attribute__((ext_vector_type(4))) unsigned int u32x4;

__device__ __forceinline__ unsigned short f2bf(float f) {
    unsigned u = __float_as_uint(f);
    unsigned r = 0x7FFFu + ((u >> 16) & 1u);
    return (unsigned short)((u + r) >> 16);
}

__device__ __forceinline__ unsigned cvtpk_bf16(float lo, float hi) {
    unsigned r;
    asm("v_cvt_pk_bf16_f32 %0, %1, %2" : "=v"(r) : "v"(lo), "v"(hi));
    return r;
}

// guaranteed single-instruction 2^x
__device__ __forceinline__ float fexp2(float x) {
    float r;
    asm("v_exp_f32 %0, %1" : "=v"(r) : "v"(x));
    return r;
}

// v_permlane32_swap_b32: a = [a_lo | b_lo], b = [a_hi | b_hi]
__device__ __forceinline__ void plswap(unsigned &a, unsigned &b) {
    asm("v_permlane32_swap_b32 %0, %1" : "+v"(a), "+v"(b));
}

__device__ __forceinline__ float xhalf_max(float v) {
    float a = v, b = v;
    asm("" : "+v"(b));
    asm("v_permlane32_swap_b32 %0, %1" : "+v"(a), "+v"(b));
    return fmaxf(a, b);
}
__device__ __forceinline__ float xhalf_sum(float v) {
    float a = v, b = v;
    asm("" : "+v"(b));
    asm("v_permlane32_swap_b32 %0, %1" : "+v"(a), "+v"(b));
    return a + b;
}

__device__ __forceinline__ void gload16(const void* g, void* l) {
    __builtin_amdgcn_global_load_lds(
        (__attribute__((address_space(1))) void*)g,
        (__attribute__((address_space(3))) void*)l,
        16, 0, 0);
}

// ---------------- fp32 -> bf16 conversion ----------------
__global__ void cvt_bf16(const float* __restrict__ in,
                         unsigned short* __restrict__ out, int n) {
    int idx = (blockIdx.x * blockDim.x + threadIdx.x) * 4;
    if (idx >= n) return;
    float4 v = *reinterpret_cast<const float4*>(in + idx);
    ushort4 o;
    o.x = f2bf(v.x); o.y = f2bf(v.y); o.z = f2bf(v.z); o.w = f2bf(v.w);
    *reinterpret_cast<ushort4*>(out + idx) = o;
}

__global__ void cvt_bf16_w4(const float* __restrict__ a, const float* __restrict__ b,
                            const float* __restrict__ c, const float* __restrict__ d,
                            unsigned short* __restrict__ oa, unsigned short* __restrict__ ob,
                            unsigned short* __restrict__ oc, unsigned short* __restrict__ od,
                            int n) {
    int idx = (blockIdx.x * blockDim.x + threadIdx.x) * 4;
    if (idx >= n) return;
    const float* in = (blockIdx.y == 0) ? a : (blockIdx.y == 1) ? b : (blockIdx.y == 2) ? c : d;
    unsigned short* out = (blockIdx.y == 0) ? oa : (blockIdx.y == 1) ? ob : (blockIdx.y == 2) ? oc : od;
    float4 v = *reinterpret_cast<const float4*>(in + idx);
    ushort4 o;
    o.x = f2bf(v.x); o.y = f2bf(v.y); o.z = f2bf(v.z); o.w = f2bf(v.w);
    *reinterpret_cast<ushort4*>(out + idx) = o;
}

// ---------------- fused QKV projection GEMM (R9-verified: BK=32) ----------------
// which 0 -> K [B,H,T,D], which 1 -> Q*scale [B,H,T,D], which 2 -> V^T [B,H,D,T]
__global__ __launch_bounds__(256) void gemm_qkv(
    const unsigned short* __restrict__ A,
    const unsigned short* __restrict__ W0,
    const unsigned short* __restrict__ W1,
    const unsigned short* __restrict__ W2,
    const float* __restrict__ b0,
    const float* __restrict__ b1,
    const float* __restrict__ b2,
    unsigned short* __restrict__ o0,   // k
    unsigned short* __restrict__ o1,   // q (pre-scaled by LOG2E/32)
    unsigned short* __restrict__ o2)   // vt
{
    __shared__ unsigned short As[128*32];
    __shared__ unsigned short Bs[128*32];
    int which = blockIdx.x >> 8;
    int bx = blockIdx.x & 255;
    int bm = bx >> 3, bn = bx & 7;
    const unsigned short* W = (which==0) ? W0 : ((which==1) ? W1 : W2);
    const float* bias = (which==0) ? b0 : ((which==1) ? b1 : b2);

    int tid = threadIdx.x;
    int lane = tid & 63;
    int fr = lane & 15, fq = lane >> 4;
    int wid = tid >> 6;
    int wr = wid >> 1, wc = wid & 1;

    int srow = tid >> 2;            // 0..63
    int scol = (tid & 3) << 3;      // 0,8,16,24
    const unsigned short* Ab = A + (size_t)(bm*128 + srow) * C_ + scol;
    const unsigned short* Wb = W + (size_t)(bn*128 + srow) * C_ + scol;

    f32x4 acc[4][4] = {};

    for (int kt = 0; kt < C_/32; ++kt) {
        int ko = kt*32;
        gload16(Ab + ko,            &As[tid*8]);
        gload16(Ab + 64*C_ + ko,    &As[2048 + tid*8]);
        gload16(Wb + ko,            &Bs[tid*8]);
        gload16(Wb + 64*C_ + ko,    &Bs[2048 + tid*8]);
        __syncthreads();
        short8 af[4], bfr[4];
        #pragma unroll
        for (int i = 0; i < 4; ++i) {
            af[i]  = *reinterpret_cast<const short8*>(&As[(wr*64 + i*16 + fr)*32 + fq*8]);
            bfr[i] = *reinterpret_cast<const short8*>(&Bs[(wc*64 + i*16 + fr)*32 + fq*8]);
        }
        #pragma unroll
        for (int i = 0; i < 4; ++i)
            #pragma unroll
            for (int j = 0; j < 4; ++j)
                acc[i][j] = __builtin_amdgcn_mfma_f32_16x16x32_bf16(af[i], bfr[j], acc[i][j], 0, 0, 0);
        __syncthreads();
    }

    // Q: fold 1/sqrt(C)=1/32 AND log2(e) so QK^T lands in log2 domain
    float sc = (which == 1) ? 0.045084220f : 1.0f;
    int mbase = bm*128 + wr*64;
    int nbase = bn*128 + wc*64;
    #pragma unroll
    for (int j = 0; j < 4; ++j) {
        int col = nbase + j*16 + fr;
        float bv = bias[col];
        int h = col >> 6, d = col & 63;
        #pragma unroll
        for (int i = 0; i < 4; ++i) {
            int r0 = mbase + i*16 + fq*4;
            #pragma unroll
            for (int r = 0; r < 4; ++r) {
                float v = (acc[i][j][r] + bv) * sc;
                int m = r0 + r;
                int b = m >> 11, t = m & (T_-1);
                unsigned short hv = f2bf(v);
                if (which == 2)
                    o2[((size_t)(b*H_ + h)*D_ + d)*T_ + t] = hv;
                else {
                    unsigned short* o = (which==0) ? o0 : o1;
                    o[((size_t)(b*H_ + h)*T_ + t)*D_ + d] = hv;
                }
            }
        }
    }
}

// ---------------- output projection GEMM (R9-verified: BK=32) ----------------
__global__ __launch_bounds__(256) void gemm_out(
    const unsigned short* __restrict__ A,   // y bf16 [M_][C_]
    const unsigned short* __restrict__ W,   // Wo bf16 [C_][C_]
    const float* __restrict__ bias,
    float* __restrict__ out)
{
    __shared__ unsigned short As[128*32];
    __shared__ unsigned short Bs[128*32];
    int bx = blockIdx.x;
    int bm = bx >> 3, bn = bx & 7;

    int tid = threadIdx.x;
    int lane = tid & 63;
    int fr = lane & 15, fq = lane >> 4;
    int wid = tid >> 6;
    int wr = wid >> 1, wc = wid & 1;

    int srow = tid >> 2;
    int scol = (tid & 3) << 3;
    const unsigned short* Ab = A + (size_t)(bm*128 + srow) * C_ + scol;
    const unsigned short* Wb = W + (size_t)(bn*128 + srow) * C_ + scol;

    f32x4 acc[4][4] = {};

    for (int kt = 0; kt < C_/32; ++kt) {
        int ko = kt*32;
        gload16(Ab + ko,            &As[tid*8]);
        gload16(Ab + 64*C_ + ko,    &As[2048 + tid*8]);
        gload16(Wb + ko,            &Bs[tid*8]);
        gload16(Wb + 64*C_ + ko,    &Bs[2048 + tid*8]);
        __syncthreads();
        short8 af[4], bfr[4];
        #pragma unroll
        for (int i = 0; i < 4; ++i) {
            af[i]  = *reinterpret_cast<const short8*>(&As[(wr*64 + i*16 + fr)*32 + fq*8]);
            bfr[i] = *reinterpret_cast<const short8*>(&Bs[(wc*64 + i*16 + fr)*32 + fq*8]);
        }
        #pragma unroll
        for (int i = 0; i < 4; ++i)
            #pragma unroll
            for (int j = 0; j < 4; ++j)
                acc[i][j] = __builtin_amdgcn_mfma_f32_16x16x32_bf16(af[i], bfr[j], acc[i][j], 0, 0, 0);
        __syncthreads();
    }

    int mbase = bm*128 + wr*64;
    int nbase = bn*128 + wc*64;
    #pragma unroll
    for (int j = 0; j < 4; ++j) {
        int col = nbase + j*16 + fr;
        float bv = bias[col];
        #pragma unroll
        for (int i = 0; i < 4; ++i) {
            int r0 = mbase + i*16 + fq*4;
            #pragma unroll
            for (int r = 0; r < 4; ++r)
                out[(size_t)(r0 + r)*C_ + col] = acc[i][j][r] + bv;
        }
    }
}

// ---------------- flash attention: staged + in-block 2-way KV split ----------------
// Block = 4 waves / 256 thr. Waves {0,1}: kv tiles [0,S+1); waves {2,3}: [S+1,2S+2).
// Wave pair (w, w+2) owns the same 64 q-rows (2 chains of 32). LDS merge at end.
__device__ __forceinline__ void attn_subtile(
    const short8 (&kf)[4], const short8 (&qf)[4],
    const short8 (&vlo)[2], const short8 (&vhi)[2],
    bool diag, int l31, int hi,
    f32x16& o0, f32x16& o1, float& m_, float& l_)
{
    // QK^T (swapped: A=K, B=Q): a0 col = q row (l31), row = kv_local
    f32x16 a0 = {};
    __builtin_amdgcn_s_setprio(1);
    a0 = __builtin_amdgcn_mfma_f32_32x32x16_bf16(kf[0], qf[0], a0, 0, 0, 0);
    a0 = __builtin_amdgcn_mfma_f32_32x32x16_bf16(kf[1], qf[1], a0, 0, 0, 0);
    a0 = __builtin_amdgcn_mfma_f32_32x32x16_bf16(kf[2], qf[2], a0, 0, 0, 0);
    a0 = __builtin_amdgcn_mfma_f32_32x32x16_bf16(kf[3], qf[3], a0, 0, 0, 0);
    __builtin_amdgcn_s_setprio(0);

    // causal mask: only the diagonal sub-tile
    if (diag) {
        #pragma unroll
        for (int r = 0; r < 16; ++r) {
            int kvl = (r&3) + 8*(r>>2) + 4*hi;
            if (kvl > l31) a0[r] = -1e30f;
        }
    }

    // row max: pairwise tree + cross-half swap
    float x0 = fmaxf(a0[0], a0[1]),   x1 = fmaxf(a0[2], a0[3]);
    float x2 = fmaxf(a0[4], a0[5]),   x3 = fmaxf(a0[6], a0[7]);
    float x4 = fmaxf(a0[8], a0[9]),   x5 = fmaxf(a0[10], a0[11]);
    float x6 = fmaxf(a0[12], a0[13]), x7 = fmaxf(a0[14], a0[15]);
    float y0 = fmaxf(x0, x1), y1 = fmaxf(x2, x3), y2 = fmaxf(x4, x5), y3 = fmaxf(x6, x7);
    float pm = fmaxf(fmaxf(y0, y1), fmaxf(y2, y3));
    pm = xhalf_max(pm);

    // defer-max (T13)
    if (!__all(pm - m_ <= 8.0f)) {
        float mn = fmaxf(m_, pm);
        float alpha = fexp2(m_ - mn);
        l_ *= alpha;
        m_ = mn;
        #pragma unroll
        for (int r = 0; r < 16; ++r) {
            int row = (r&3) + 8*(r>>2) + 4*hi;
            float ar = __shfl(alpha, row);
            o0[r] *= ar;
            o1[r] *= ar;
        }
    }

    // P = exp2(s - m); row sum via pairwise tree + cross-half swap
    #pragma unroll
    for (int r = 0; r < 16; ++r)
        a0[r] = fexp2(a0[r] - m_);
    float s0 = a0[0]+a0[1],  s1 = a0[2]+a0[3],  s2 = a0[4]+a0[5],   s3 = a0[6]+a0[7];
    float s4 = a0[8]+a0[9],  s5 = a0[10]+a0[11], s6 = a0[12]+a0[13], s7 = a0[14]+a0[15];
    float u0 = s0+s1, u1 = s2+s3, u2 = s4+s5, u3 = s6+s7;
    float rs = (u0+u1) + (u2+u3);
    rs = xhalf_sum(rs);
    l_ += rs;

    // pack P to bf16 pairs
    unsigned pk_[8];
    #pragma unroll
    for (int jj = 0; jj < 8; ++jj)
        pk_[jj] = cvtpk_bf16(a0[2*jj], a0[2*jj+1]);

    // PV: A-frag redistribution via permlane32_swap
    #pragma unroll
    for (int kb = 0; kb < 2; ++kb) {
        unsigned fx = pk_[4*kb+0], fz = pk_[4*kb+2];
        unsigned fy = pk_[4*kb+1], fw = pk_[4*kb+3];
        plswap(fx, fz);
        plswap(fy, fw);
        u32x4 wv;
        wv.x = fx; wv.y = fy; wv.z = fz; wv.w = fw;
        short8 pfrag = __builtin_bit_cast(short8, wv);
        __builtin_amdgcn_s_setprio(1);
        o0 = __builtin_amdgcn_mfma_f32_32x32x16_bf16(pfrag, vlo[kb], o0, 0, 0, 0);
        o1 = __builtin_amdgcn_mfma_f32_32x32x16_bf16(pfrag, vhi[kb], o1, 0, 0, 0);
        __builtin_amdgcn_s_setprio(0);
    }
}

__global__ __launch_bounds__(256, 2) void flash_attn(
    const unsigned short* __restrict__ q,
    const unsigned short* __restrict__ k,
    const unsigned short* __restrict__ vt,
    unsigned short* __restrict__ y)
{
    // staging: [buf][tensor][4096 shorts]; tensors: 0=K_lo 1=K_hi 2=V_lo 3=V_hi (64 KB)
    __shared__ __align__(16) unsigned short ST[2][4][4096];
    // merge overlay (used only after the final compute barrier):
    float* oP  = reinterpret_cast<float*>(&ST[0][0][0]);   // [4 sets][32 rows][68]
    float* mlP = oP + 4*32*68;                             // m: [set*32+l31], l: +128

    int tid = threadIdx.x, lane = tid & 63, w = tid >> 6;
    int l31 = lane & 31, hi = lane >> 5, rsw = l31 & 7;
    int role = w >> 1, pair = w & 1;
    int bid = blockIdx.x;

    // balanced complementary mapping: co-resident blocks (bid, bid+256) have S summing to 15
    int half = bid >> 8;              // 0 or 1
    int idx  = bid & 255;
    int bh   = (idx & 7)*4 + ((idx >> 3) & 3);   // 4 heads per XCD
    int sidx = idx >> 5;              // 0..7
    int S    = half ? sidx : (15 - sidx);        // heavy half first

    const unsigned short* kp = k  + (size_t)bh*T_*D_;
    const unsigned short* vp = vt + (size_t)bh*D_*T_;

    int rowbase = S*128 + pair*64;    // this wave-pair's first q row
    const unsigned short* qp = q + ((size_t)bh*T_ + rowbase) * D_;

    short8 qf0[4], qf1[4];
    #pragma unroll
    for (int dk = 0; dk < 4; ++dk) {
        qf0[dk] = *reinterpret_cast<const short8*>(qp + (size_t)l31*D_        + dk*16 + hi*8);
        qf1[dk] = *reinterpret_cast<const short8*>(qp + (size_t)(32 + l31)*D_ + dk*16 + hi*8);
    }

    f32x16 o00 = {}, o01 = {}, o10 = {}, o11 = {};
    float m0 = -1e30f, l0 = 0.f, m1 = -1e30f, l1 = 0.f;

    int lim0 = 4*S + 2*pair;          // chain0 diag sub-tile (global g)
    int lim1 = lim0 + 1;              // chain1
    int niter = S + 1;                // tiles per stream

    // stage iteration ii: low tile = ii, high tile = S+1+ii (512 chunks/tensor)
    #define STAGE(ii, bufi)                                                            \
    {                                                                                  \
        _Pragma("unroll")                                                              \
        for (int jj = 0; jj < 2; ++jj) {                                               \
            int c2 = tid + jj*256;                                                     \
            int row_ = c2 >> 3;                                                        \
            int slot_ = (c2 & 7) ^ (row_ & 7);                                         \
            int tl_ = (ii), th_ = S + 1 + (ii);                                        \
            gload16(kp + ((size_t)(tl_*64 + row_))*D_ + slot_*8, &ST[bufi][0][c2*8]);  \
            gload16(kp + ((size_t)(th_*64 + row_))*D_ + slot_*8, &ST[bufi][1][c2*8]);  \
            gload16(vp + (size_t)row_*T_ + tl_*64 + slot_*8,     &ST[bufi][2][c2*8]);  \
            gload16(vp + (size_t)row_*T_ + th_*64 + slot_*8,     &ST[bufi][3][c2*8]);  \
        }                                                                              \
    }

    STAGE(0, 0);
    __syncthreads();

    for (int i = 0; i < niter; ++i) {
        int bufi = i & 1;
        if (i + 1 < niter) STAGE(i + 1, bufi ^ 1);

        const unsigned short* Kl = &ST[bufi][role][0];
        const unsigned short* Vl = &ST[bufi][2 + role][0];
        int t = role ? (S + 1 + i) : i;

        #pragma unroll
        for (int st = 0; st < 2; ++st) {
            int g = 2*t + st;
            if (g <= lim1) {
                short8 kf[4];
                const unsigned short* kr = Kl + (st*32 + l31)*64;
                #pragma unroll
                for (int dk = 0; dk < 4; ++dk)
                    kf[dk] = *reinterpret_cast<const short8*>(kr + (((dk<<1)|hi) ^ rsw)*8);
                short8 vlo[2], vhi[2];
                const unsigned short* vr0 = Vl + l31*64;
                const unsigned short* vr1 = Vl + (32 + l31)*64;
                #pragma unroll
                for (int kb = 0; kb < 2; ++kb) {
                    int sl = (((st<<2) | (kb<<1) | hi) ^ rsw) * 8;
                    vlo[kb] = *reinterpret_cast<const short8*>(vr0 + sl);
                    vhi[kb] = *reinterpret_cast<const short8*>(vr1 + sl);
                }
                if (g <= lim0)
                    attn_subtile(kf, qf0, vlo, vhi, g == lim0, l31, hi, o00, o01, m0, l0);
                attn_subtile(kf, qf1, vlo, vhi, g == lim1, l31, hi, o10, o11, m1, l1);
            }
        }
        __syncthreads();
    }
    #undef STAGE

    // ---- merge the two KV halves (low waves store; high waves combine + write) ----
    if (!role) {
        int s0 = pair*2, s1 = pair*2 + 1;
        #pragma unroll
        for (int rr = 0; rr < 16; ++rr) {
            int crow = (rr&3) + 8*(rr>>2) + 4*hi;
            oP[(s0*32 + crow)*68 + l31]      = o00[rr];
            oP[(s0*32 + crow)*68 + 32 + l31] = o01[rr];
            oP[(s1*32 + crow)*68 + l31]      = o10[rr];
            oP[(s1*32 + crow)*68 + 32 + l31] = o11[rr];
        }
        if (!hi) {
            mlP[s0*32 + l31]       = m0;
            mlP[128 + s0*32 + l31] = l0;
            mlP[s1*32 + l31]       = m1;
            mlP[128 + s1*32 + l31] = l1;
        }
    }
    __syncthreads();
    if (role) {
        int b = bh >> 4, h = bh & 15;
        #pragma unroll
        for (int qq = 0; qq < 2; ++qq) {
            int set = pair*2 + qq;
            const f32x16& po0 = qq ? o10 : o00;
            const f32x16& po1 = qq ? o11 : o01;
            float m_ = qq ? m1 : m0;
            float l_ = qq ? l1 : l0;

            float mA = mlP[set*32 + l31];
            float lA = mlP[128 + set*32 + l31];
            float mN = fmaxf(mA, m_);
            float aA = fexp2(mA - mN);
            float aB = fexp2(m_ - mN);
            float lN = lA*aA + l_*aB;
            float inv = 1.0f / lN;
            float cA = aA * inv, cB = aB * inv;

            #pragma unroll
            for (int rr = 0; rr < 16; ++rr) {
                int crow = (rr&3) + 8*(rr>>2) + 4*hi;
                float cAr = __shfl(cA, crow);
                float cBr = __shfl(cB, crow);
                float vA0 = oP[(set*32 + crow)*68 + l31];
                float vA1 = oP[(set*32 + crow)*68 + 32 + l31];
                int trow = rowbase + qq*32 + crow;
                size_t base = ((size_t)(b*T_ + trow))*C_ + h*64;
                y[base + l31]      = f2bf(vA0*cAr + po0[rr]*cBr);
                y[base + 32 + l31] = f2bf(vA1*cAr + po1[rr]*cBr);
            }
        }
    }
}

extern "C" void kernel_launch(void* const* d_in, const int* in_sizes, int n_in,
                              void* d_out, int out_size, void* d_ws, size_t ws_size,
                              hipStream_t stream) {
    const float* x  = (const float*)d_in[0];
    const float* Wk = (const float*)d_in[1];
    const float* bk = (const float*)d_in[2];
    const float* Wq = (const float*)d_in[3];
    const float* bq = (const float*)d_in[4];
    const float* Wv = (const float*)d_in[5];
    const float* bv = (const float*)d_in[6];
    const float* Wo = (const float*)d_in[7];
    const float* bo = (const float*)d_in[8];
    float* out = (float*)d_out;

    char* ws = (char*)d_ws;
    unsigned short* xb  = (unsigned short*)(ws);                    // 8MB
    unsigned short* wkb = (unsigned short*)(ws + ((size_t)8  << 20));
    unsigned short* wqb = (unsigned short*)(ws + ((size_t)10 << 20));
    unsigned short* wvb = (unsigned short*)(ws + ((size_t)12 << 20));
    unsigned short* wob = (unsigned short*)(ws + ((size_t)14 << 20));
    unsigned short* qb  = (unsigned short*)(ws + ((size_t)16 << 20)); // [B,H,T,D]
    unsigned short* kb  = (unsigned short*)(ws + ((size_t)24 << 20)); // [B,H,T,D]
    unsigned short* vtb = (unsigned short*)(ws + ((size_t)32 << 20)); // [B,H,D,T]
    unsigned short* yb  = (unsigned short*)(ws + ((size_t)40 << 20)); // [B*T,C]

    const int nx = B_*T_*C_;   // 4M
    const int nw = C_*C_;      // 1M

    cvt_bf16<<<dim3(nx/4/256), dim3(256), 0, stream>>>(x, xb, nx);
    cvt_bf16_w4<<<dim3(nw/4/256, 4), dim3(256), 0, stream>>>(
        Wk, Wq, Wv, Wo, wkb, wqb, wvb, wob, nw);

    gemm_qkv<<<dim3(768), dim3(256), 0, stream>>>(xb, wkb, wqb, wvb, bk, bq, bv, kb, qb, vtb);

    flash_attn<<<dim3(512), dim3(256), 0, stream>>>(qb, kb, vtb, yb);

    gemm_out<<<dim3(256), dim3(256), 0, stream>>>(yb, wob, bo, out);
}